// Round 4
// baseline (159.546 us; speedup 1.0000x reference)
//
#include <hip/hip_runtime.h>

// MarginDevianceLoss on MI355X.
// Pipeline: f32->f16 convert -> MFMA Gram (symmetric: upper-triangle blocks
// only, mirror-write transpose) -> per-row stats+loss (one wave/row) -> final.
// ws layout: [0,8MB) Xh fp16 [4096][1024]; [8MB,40MB) simh fp16 [4096][4096];
//            [40MB,+64B) float accumulators. Requires ws_size >= ~42MB.

#define N_ROWS 4096
#define DIM    1024
#define BM     128
#define BK     64

typedef _Float16 half_t;
typedef __attribute__((ext_vector_type(8))) _Float16 half8;
typedef __attribute__((ext_vector_type(4))) float f32x4;
typedef __attribute__((ext_vector_type(4))) unsigned short ushort4v;

#define XH_BYTES  ((size_t)N_ROWS * DIM * 2)           // 8 MB
#define SIM_BYTES ((size_t)N_ROWS * N_ROWS * 2)        // 32 MB

__device__ __forceinline__ unsigned short f2h_bits(float f) {
    half_t h = (half_t)f;
    return __builtin_bit_cast(unsigned short, h);
}
__device__ __forceinline__ float h2f_bits(unsigned short u) {
    half_t h = __builtin_bit_cast(half_t, u);
    return (float)h;
}
// softplus via native v_exp/v_log (fast, ~1e-6 rel err; threshold is 1.5e-2)
__device__ __forceinline__ float sp_fast(float x) {
    return fmaxf(x, 0.f) + __logf(1.f + __expf(-fabsf(x)));
}
// full-wave (64-lane) butterfly sum; result in all lanes
__device__ __forceinline__ float wred(float v) {
#pragma unroll
    for (int m = 1; m < 64; m <<= 1) v += __shfl_xor(v, m, 64);
    return v;
}

// ---------------- convert: fp32 -> fp16, also zero the accumulators ----------
__global__ __launch_bounds__(256) void k_convert(const float* __restrict__ x,
                                                 unsigned short* __restrict__ xh,
                                                 float* __restrict__ accum) {
    if (blockIdx.x == 0 && threadIdx.x < 8) accum[threadIdx.x] = 0.f;
    int idx = blockIdx.x * 256 + threadIdx.x;          // 524288 threads, 8 elems each
    const float4* x4 = reinterpret_cast<const float4*>(x);
    float4 a = x4[2 * idx];
    float4 b = x4[2 * idx + 1];
    half8 h;
    h[0] = (half_t)a.x; h[1] = (half_t)a.y; h[2] = (half_t)a.z; h[3] = (half_t)a.w;
    h[4] = (half_t)b.x; h[5] = (half_t)b.y; h[6] = (half_t)b.z; h[7] = (half_t)b.w;
    *reinterpret_cast<half8*>(xh + 8 * idx) = h;
}

// ---------------- GEMM: sim = Xh * Xh^T (upper-triangle blocks + mirror) ------
// 128x128 tile, BK=64, 4 waves (2x2), each wave 64x64 via 4x4 frags of 16x16x32.
__global__ __launch_bounds__(256) void k_gemm(const unsigned short* __restrict__ Xh,
                                              unsigned short* __restrict__ simh) {
    const int by = blockIdx.y, bx = blockIdx.x;
    if (bx < by) return;                               // symmetric: skip lower
    __shared__ __align__(16) unsigned short As[BM * BK];
    __shared__ __align__(16) unsigned short Bs[BM * BK];
    const int t = threadIdx.x;
    const int lane = t & 63;
    const int wave = t >> 6;
    const int wr = wave >> 1, wc = wave & 1;
    const int brow = by * BM;
    const int bcol = bx * BM;

    f32x4 acc[4][4];
#pragma unroll
    for (int m = 0; m < 4; ++m)
#pragma unroll
        for (int n = 0; n < 4; ++n) acc[m][n] = (f32x4){0.f, 0.f, 0.f, 0.f};

    const char* xb = reinterpret_cast<const char*>(Xh);

    for (int kt = 0; kt < DIM / BK; ++kt) {
#pragma unroll
        for (int i = 0; i < 4; ++i) {
            int off = i * 4096 + t * 16;               // byte offset in 16KB tile
            int r   = off >> 7;                        // /128 bytes per row
            int cb  = off & 127;
            const char* gA = xb + (size_t)(brow + r) * (DIM * 2) + kt * (BK * 2) + cb;
            const char* gB = xb + (size_t)(bcol + r) * (DIM * 2) + kt * (BK * 2) + cb;
            __builtin_amdgcn_global_load_lds(
                (const __attribute__((address_space(1))) void*)gA,
                (__attribute__((address_space(3))) void*)((char*)As + off), 16, 0, 0);
            __builtin_amdgcn_global_load_lds(
                (const __attribute__((address_space(1))) void*)gB,
                (__attribute__((address_space(3))) void*)((char*)Bs + off), 16, 0, 0);
        }
        __syncthreads();

#pragma unroll
        for (int kk = 0; kk < 2; ++kk) {
            half8 a[4], b[4];
            const int kf = kk * 32 + (lane >> 4) * 8;
#pragma unroll
            for (int m = 0; m < 4; ++m) {
                int row = wr * 64 + m * 16 + (lane & 15);
                a[m] = *reinterpret_cast<const half8*>(As + row * BK + kf);
            }
#pragma unroll
            for (int n = 0; n < 4; ++n) {
                int row = wc * 64 + n * 16 + (lane & 15);
                b[n] = *reinterpret_cast<const half8*>(Bs + row * BK + kf);
            }
#pragma unroll
            for (int m = 0; m < 4; ++m)
#pragma unroll
                for (int n = 0; n < 4; ++n)
                    acc[m][n] = __builtin_amdgcn_mfma_f32_16x16x32_f16(a[m], b[n], acc[m][n], 0, 0, 0);
        }
        __syncthreads();
    }

    // epilogue: C/D layout col=lane&15, row=(lane>>4)*4+reg  [verified m89]
    const int fr = lane & 15, fq = lane >> 4;
#pragma unroll
    for (int m = 0; m < 4; ++m) {
#pragma unroll
        for (int n = 0; n < 4; ++n) {
            int col  = bcol + wc * 64 + n * 16 + fr;
            int row0 = brow + wr * 64 + m * 16 + fq * 4;
#pragma unroll
            for (int r = 0; r < 4; ++r)
                simh[(size_t)(row0 + r) * N_ROWS + col] = f2h_bits(acc[m][n][r]);
            if (bx != by) {
                // mirror tile: sim[col][row0..row0+3] = same values (exact
                // transpose; identical products, identical k-order). Lane holds
                // 4 consecutive rows of one column -> one packed 8B store.
                ushort4v p;
                p[0] = f2h_bits(acc[m][n][0]);
                p[1] = f2h_bits(acc[m][n][1]);
                p[2] = f2h_bits(acc[m][n][2]);
                p[3] = f2h_bits(acc[m][n][3]);
                *reinterpret_cast<ushort4v*>(simh + (size_t)col * N_ROWS + row0) = p;
            }
        }
    }
}

// ---------------- per-row stats + loss: one wave per row ----------------------
__global__ __launch_bounds__(256) void k_stats(const unsigned short* __restrict__ simh,
                                               const int* __restrict__ targets,
                                               float* __restrict__ accum) {
    __shared__ float part[4][8];
    const int t = threadIdx.x;
    const int lane = t & 63;
    const int w = t >> 6;
    const int i = blockIdx.x * 4 + w;                  // this wave's row
    const int ti = targets[i];

    const uint4* r4  = reinterpret_cast<const uint4*>(simh + (size_t)i * N_ROWS);
    const int4*  tg4 = reinterpret_cast<const int4*>(targets);

    float s[8][8];
    unsigned int mpos[8];
    float ps = 0.f, ps2 = 0.f, ns = 0.f, ns2 = 0.f, pc = 0.f, nc = 0.f;

#pragma unroll
    for (int j = 0; j < 8; ++j) {
        const int ci = j * 64 + lane;                  // uint4 index; cols 8*ci..+7
        uint4 v  = r4[ci];
        int4 ta = tg4[2 * ci];
        int4 tb = tg4[2 * ci + 1];
        unsigned m = 0;
        m |= (ta.x == ti) ? 1u   : 0u;
        m |= (ta.y == ti) ? 2u   : 0u;
        m |= (ta.z == ti) ? 4u   : 0u;
        m |= (ta.w == ti) ? 8u   : 0u;
        m |= (tb.x == ti) ? 16u  : 0u;
        m |= (tb.y == ti) ? 32u  : 0u;
        m |= (tb.z == ti) ? 64u  : 0u;
        m |= (tb.w == ti) ? 128u : 0u;
        mpos[j] = m;
        unsigned int uw0 = v.x, uw1 = v.y, uw2 = v.z, uw3 = v.w;
        s[j][0] = h2f_bits((unsigned short)(uw0 & 0xffff));
        s[j][1] = h2f_bits((unsigned short)(uw0 >> 16));
        s[j][2] = h2f_bits((unsigned short)(uw1 & 0xffff));
        s[j][3] = h2f_bits((unsigned short)(uw1 >> 16));
        s[j][4] = h2f_bits((unsigned short)(uw2 & 0xffff));
        s[j][5] = h2f_bits((unsigned short)(uw2 >> 16));
        s[j][6] = h2f_bits((unsigned short)(uw3 & 0xffff));
        s[j][7] = h2f_bits((unsigned short)(uw3 >> 16));
        const int c0 = ci * 8;
#pragma unroll
        for (int e = 0; e < 8; ++e) {
            float sv = s[j][e];
            bool pos  = (m >> e) & 1;
            bool diag = (c0 + e) == i;
            if (pos) {
                if (!diag) { ps += sv; ps2 = fmaf(sv, sv, ps2); pc += 1.f; }
            } else {
                ns += sv; ns2 = fmaf(sv, sv, ns2); nc += 1.f;
            }
        }
    }
    ps = wred(ps); ps2 = wred(ps2); pc = wred(pc);
    ns = wred(ns); ns2 = wred(ns2); nc = wred(nc);

    float pmean = ps / pc;
    float pstd  = sqrtf(fmaxf(ps2 / pc - pmean * pmean, 0.f));
    float nmean = ns / nc;
    float nstd  = sqrtf(fmaxf(ns2 / nc - nmean * nmean, 0.f));
    float inter = (pstd * pmean + nstd * nmean) / (pstd + nstd);
    float thr   = pmean - 1.5f * pstd;

    float pl = 0.f, nl = 0.f, kc = 0.f;
#pragma unroll
    for (int j = 0; j < 8; ++j) {
        const int c0 = (j * 64 + lane) * 8;
        unsigned m = mpos[j];
#pragma unroll
        for (int e = 0; e < 8; ++e) {
            float sv = s[j][e];
            float d  = sv - inter;
            bool pos  = (m >> e) & 1;
            bool diag = (c0 + e) == i;
            if (pos) {
                if (!diag) pl += sp_fast(-2.f * d);
            } else if (sv > thr) {
                kc += 1.f;
                nl += sp_fast(50.f * d);
            }
        }
    }
    pl = wred(pl); nl = wred(nl); kc = wred(kc);

    if (lane == 0) {
        bool valid = kc >= 1.f;
        part[w][0] = valid ? (pl / pc + 0.04f * nl / fmaxf(kc, 1.f)) : 0.f;
        part[w][1] = valid ? 0.f : 1.f;
        part[w][2] = ps;
        part[w][3] = pc;
        part[w][4] = ns;
        part[w][5] = nc;
    }
    __syncthreads();
    if (t < 6) {
        float v = part[0][t] + part[1][t] + part[2][t] + part[3][t];
        atomicAdd(&accum[t], v);
    }
}

// ---------------- finalize ----------------------------------------------------
__global__ void k_final(const float* __restrict__ acc, float* __restrict__ out) {
    if (threadIdx.x == 0) {
        out[0] = acc[0] / (float)N_ROWS;   // loss
        out[1] = acc[1] / (float)N_ROWS;   // prec
        out[2] = acc[2] / acc[3];          // pos_d
        out[3] = acc[4] / acc[5];          // neg_d
    }
}

extern "C" void kernel_launch(void* const* d_in, const int* in_sizes, int n_in,
                              void* d_out, int out_size, void* d_ws, size_t ws_size,
                              hipStream_t stream) {
    const float* x       = (const float*)d_in[0];
    const int*   targets = (const int*)d_in[1];
    float*       out     = (float*)d_out;
    char*        ws      = (char*)d_ws;

    unsigned short* Xh    = (unsigned short*)ws;
    unsigned short* simh  = (unsigned short*)(ws + XH_BYTES);
    float*          accum = (float*)(ws + XH_BYTES + SIM_BYTES);

    k_convert<<<2048, 256, 0, stream>>>(x, Xh, accum);
    dim3 g(N_ROWS / BM, N_ROWS / BM);
    k_gemm<<<g, 256, 0, stream>>>(Xh, simh);
    k_stats<<<N_ROWS / 4, 256, 0, stream>>>(simh, targets, accum);
    k_final<<<1, 64, 0, stream>>>(accum, out);
}

// Round 6
// 157.887 us; speedup vs baseline: 1.0105x; 1.0105x over previous
//
#include <hip/hip_runtime.h>

// MarginDevianceLoss on MI355X.
// Pipeline: f32->f16 convert -> MFMA Gram (528 upper-triangle tiles, 1D grid
// with triangular decode + XCD chunk swizzle, mirror-write transpose)
//        -> per-row stats+loss (one wave/row) -> finalize.
// ws layout: [0,8MB) Xh fp16 [4096][1024]; [8MB,40MB) simh fp16 [4096][4096];
//            [40MB,+64B) float accumulators. Requires ws_size >= ~42MB.

#define N_ROWS 4096
#define DIM    1024
#define BM     128
#define BK     64
#define NTILE  32              // N_ROWS / BM
#define NUT    528             // NTILE*(NTILE+1)/2 upper-triangle tiles

typedef _Float16 half_t;
typedef __attribute__((ext_vector_type(8))) _Float16 half8;
typedef __attribute__((ext_vector_type(4))) float f32x4;
typedef __attribute__((ext_vector_type(4))) unsigned short ushort4v;

#define XH_BYTES  ((size_t)N_ROWS * DIM * 2)           // 8 MB
#define SIM_BYTES ((size_t)N_ROWS * N_ROWS * 2)        // 32 MB

__device__ __forceinline__ unsigned short f2h_bits(float f) {
    half_t h = (half_t)f;
    return __builtin_bit_cast(unsigned short, h);
}
__device__ __forceinline__ float h2f_bits(unsigned short u) {
    half_t h = __builtin_bit_cast(half_t, u);
    return (float)h;
}
// softplus via native v_exp/v_log (fast, ~1e-6 rel err; threshold is 1.5e-2)
__device__ __forceinline__ float sp_fast(float x) {
    return fmaxf(x, 0.f) + __logf(1.f + __expf(-fabsf(x)));
}
// full-wave (64-lane) butterfly sum; result in all lanes
__device__ __forceinline__ float wred(float v) {
#pragma unroll
    for (int m = 1; m < 64; m <<= 1) v += __shfl_xor(v, m, 64);
    return v;
}

// ---------------- convert: fp32 -> fp16, also zero the accumulators ----------
__global__ __launch_bounds__(256) void k_convert(const float* __restrict__ x,
                                                 unsigned short* __restrict__ xh,
                                                 float* __restrict__ accum) {
    if (blockIdx.x == 0 && threadIdx.x < 8) accum[threadIdx.x] = 0.f;
    int idx = blockIdx.x * 256 + threadIdx.x;          // 524288 threads, 8 elems each
    const float4* x4 = reinterpret_cast<const float4*>(x);
    float4 a = x4[2 * idx];
    float4 b = x4[2 * idx + 1];
    half8 h;
    h[0] = (half_t)a.x; h[1] = (half_t)a.y; h[2] = (half_t)a.z; h[3] = (half_t)a.w;
    h[4] = (half_t)b.x; h[5] = (half_t)b.y; h[6] = (half_t)b.z; h[7] = (half_t)b.w;
    *reinterpret_cast<half8*>(xh + 8 * idx) = h;
}

// ---------------- GEMM: sim = Xh * Xh^T (upper-triangle tiles + mirror) -------
// 1D grid of 528 tiles; triangular decode; 128x128 tile, BK=64, 4 waves (2x2),
// each wave 64x64 via 4x4 frags of 16x16x32.
__global__ __launch_bounds__(256) void k_gemm(const unsigned short* __restrict__ Xh,
                                              unsigned short* __restrict__ simh) {
    // XCD chunk swizzle (bijective: 528 % 8 == 0, 66 tiles per XCD)
    const int k0 = blockIdx.x;
    const int k  = (k0 & 7) * (NUT / 8) + (k0 >> 3);
    // triangular decode: row r with S(r)=r*(65-r)/2 tiles before it
    int r = (int)((65.0f - sqrtf(4225.0f - 8.0f * (float)k)) * 0.5f);
    while ((r + 1) * (65 - (r + 1)) / 2 <= k) ++r;
    while (r * (65 - r) / 2 > k) --r;
    const int by = r;
    const int bx = r + (k - r * (65 - r) / 2);

    __shared__ __align__(16) unsigned short As[BM * BK];
    __shared__ __align__(16) unsigned short Bs[BM * BK];
    const int t = threadIdx.x;
    const int lane = t & 63;
    const int wave = t >> 6;
    const int wr = wave >> 1, wc = wave & 1;
    const int brow = by * BM;
    const int bcol = bx * BM;

    f32x4 acc[4][4];
#pragma unroll
    for (int m = 0; m < 4; ++m)
#pragma unroll
        for (int n = 0; n < 4; ++n) acc[m][n] = (f32x4){0.f, 0.f, 0.f, 0.f};

    const char* xb = reinterpret_cast<const char*>(Xh);

    for (int kt = 0; kt < DIM / BK; ++kt) {
#pragma unroll
        for (int i = 0; i < 4; ++i) {
            int off = i * 4096 + t * 16;               // byte offset in 16KB tile
            int rr  = off >> 7;                        // /128 bytes per row
            int cb  = off & 127;
            const char* gA = xb + (size_t)(brow + rr) * (DIM * 2) + kt * (BK * 2) + cb;
            const char* gB = xb + (size_t)(bcol + rr) * (DIM * 2) + kt * (BK * 2) + cb;
            __builtin_amdgcn_global_load_lds(
                (const __attribute__((address_space(1))) void*)gA,
                (__attribute__((address_space(3))) void*)((char*)As + off), 16, 0, 0);
            __builtin_amdgcn_global_load_lds(
                (const __attribute__((address_space(1))) void*)gB,
                (__attribute__((address_space(3))) void*)((char*)Bs + off), 16, 0, 0);
        }
        __syncthreads();

#pragma unroll
        for (int kk = 0; kk < 2; ++kk) {
            half8 a[4], b[4];
            const int kf = kk * 32 + (lane >> 4) * 8;
#pragma unroll
            for (int m = 0; m < 4; ++m) {
                int row = wr * 64 + m * 16 + (lane & 15);
                a[m] = *reinterpret_cast<const half8*>(As + row * BK + kf);
            }
#pragma unroll
            for (int n = 0; n < 4; ++n) {
                int row = wc * 64 + n * 16 + (lane & 15);
                b[n] = *reinterpret_cast<const half8*>(Bs + row * BK + kf);
            }
#pragma unroll
            for (int m = 0; m < 4; ++m)
#pragma unroll
                for (int n = 0; n < 4; ++n)
                    acc[m][n] = __builtin_amdgcn_mfma_f32_16x16x32_f16(a[m], b[n], acc[m][n], 0, 0, 0);
        }
        __syncthreads();
    }

    // epilogue: C/D layout col=lane&15, row=(lane>>4)*4+reg  [verified m89]
    const int fr = lane & 15, fq = lane >> 4;
#pragma unroll
    for (int m = 0; m < 4; ++m) {
#pragma unroll
        for (int n = 0; n < 4; ++n) {
            int col  = bcol + wc * 64 + n * 16 + fr;
            int row0 = brow + wr * 64 + m * 16 + fq * 4;
#pragma unroll
            for (int rr = 0; rr < 4; ++rr)
                simh[(size_t)(row0 + rr) * N_ROWS + col] = f2h_bits(acc[m][n][rr]);
            if (bx != by) {
                // mirror tile: sim[col][row0..row0+3] (exact transpose; identical
                // products, identical k-order). One packed 8B store per frag col.
                ushort4v p;
                p[0] = f2h_bits(acc[m][n][0]);
                p[1] = f2h_bits(acc[m][n][1]);
                p[2] = f2h_bits(acc[m][n][2]);
                p[3] = f2h_bits(acc[m][n][3]);
                *reinterpret_cast<ushort4v*>(simh + (size_t)col * N_ROWS + row0) = p;
            }
        }
    }
}

// ---------------- per-row stats + loss: one wave per row ----------------------
__global__ __launch_bounds__(256) void k_stats(const unsigned short* __restrict__ simh,
                                               const int* __restrict__ targets,
                                               float* __restrict__ accum) {
    __shared__ float part[4][8];
    const int t = threadIdx.x;
    const int lane = t & 63;
    const int w = t >> 6;
    const int i = blockIdx.x * 4 + w;                  // this wave's row
    const int ti = targets[i];

    const uint4* r4  = reinterpret_cast<const uint4*>(simh + (size_t)i * N_ROWS);
    const int4*  tg4 = reinterpret_cast<const int4*>(targets);

    float s[8][8];
    unsigned int mpos[8];
    float ps = 0.f, ps2 = 0.f, ns = 0.f, ns2 = 0.f, pc = 0.f, nc = 0.f;

#pragma unroll
    for (int j = 0; j < 8; ++j) {
        const int ci = j * 64 + lane;                  // uint4 index; cols 8*ci..+7
        uint4 v  = r4[ci];
        int4 ta = tg4[2 * ci];
        int4 tb = tg4[2 * ci + 1];
        unsigned m = 0;
        m |= (ta.x == ti) ? 1u   : 0u;
        m |= (ta.y == ti) ? 2u   : 0u;
        m |= (ta.z == ti) ? 4u   : 0u;
        m |= (ta.w == ti) ? 8u   : 0u;
        m |= (tb.x == ti) ? 16u  : 0u;
        m |= (tb.y == ti) ? 32u  : 0u;
        m |= (tb.z == ti) ? 64u  : 0u;
        m |= (tb.w == ti) ? 128u : 0u;
        mpos[j] = m;
        unsigned int uw0 = v.x, uw1 = v.y, uw2 = v.z, uw3 = v.w;
        s[j][0] = h2f_bits((unsigned short)(uw0 & 0xffff));
        s[j][1] = h2f_bits((unsigned short)(uw0 >> 16));
        s[j][2] = h2f_bits((unsigned short)(uw1 & 0xffff));
        s[j][3] = h2f_bits((unsigned short)(uw1 >> 16));
        s[j][4] = h2f_bits((unsigned short)(uw2 & 0xffff));
        s[j][5] = h2f_bits((unsigned short)(uw2 >> 16));
        s[j][6] = h2f_bits((unsigned short)(uw3 & 0xffff));
        s[j][7] = h2f_bits((unsigned short)(uw3 >> 16));
        const int c0 = ci * 8;
#pragma unroll
        for (int e = 0; e < 8; ++e) {
            float sv = s[j][e];
            bool pos  = (m >> e) & 1;
            bool diag = (c0 + e) == i;
            if (pos) {
                if (!diag) { ps += sv; ps2 = fmaf(sv, sv, ps2); pc += 1.f; }
            } else {
                ns += sv; ns2 = fmaf(sv, sv, ns2); nc += 1.f;
            }
        }
    }
    ps = wred(ps); ps2 = wred(ps2); pc = wred(pc);
    ns = wred(ns); ns2 = wred(ns2); nc = wred(nc);

    float pmean = ps / pc;
    float pstd  = sqrtf(fmaxf(ps2 / pc - pmean * pmean, 0.f));
    float nmean = ns / nc;
    float nstd  = sqrtf(fmaxf(ns2 / nc - nmean * nmean, 0.f));
    float inter = (pstd * pmean + nstd * nmean) / (pstd + nstd);
    float thr   = pmean - 1.5f * pstd;

    float pl = 0.f, nl = 0.f, kc = 0.f;
#pragma unroll
    for (int j = 0; j < 8; ++j) {
        const int c0 = (j * 64 + lane) * 8;
        unsigned m = mpos[j];
#pragma unroll
        for (int e = 0; e < 8; ++e) {
            float sv = s[j][e];
            float d  = sv - inter;
            bool pos  = (m >> e) & 1;
            bool diag = (c0 + e) == i;
            if (pos) {
                if (!diag) pl += sp_fast(-2.f * d);
            } else if (sv > thr) {
                kc += 1.f;
                nl += sp_fast(50.f * d);
            }
        }
    }
    pl = wred(pl); nl = wred(nl); kc = wred(kc);

    if (lane == 0) {
        bool valid = kc >= 1.f;
        part[w][0] = valid ? (pl / pc + 0.04f * nl / fmaxf(kc, 1.f)) : 0.f;
        part[w][1] = valid ? 0.f : 1.f;
        part[w][2] = ps;
        part[w][3] = pc;
        part[w][4] = ns;
        part[w][5] = nc;
    }
    __syncthreads();
    if (t < 6) {
        float v = part[0][t] + part[1][t] + part[2][t] + part[3][t];
        atomicAdd(&accum[t], v);
    }
}

// ---------------- finalize ----------------------------------------------------
__global__ void k_final(const float* __restrict__ acc, float* __restrict__ out) {
    if (threadIdx.x == 0) {
        out[0] = acc[0] / (float)N_ROWS;   // loss
        out[1] = acc[1] / (float)N_ROWS;   // prec
        out[2] = acc[2] / acc[3];          // pos_d
        out[3] = acc[4] / acc[5];          // neg_d
    }
}

extern "C" void kernel_launch(void* const* d_in, const int* in_sizes, int n_in,
                              void* d_out, int out_size, void* d_ws, size_t ws_size,
                              hipStream_t stream) {
    const float* x       = (const float*)d_in[0];
    const int*   targets = (const int*)d_in[1];
    float*       out     = (float*)d_out;
    char*        ws      = (char*)d_ws;

    unsigned short* Xh    = (unsigned short*)ws;
    unsigned short* simh  = (unsigned short*)(ws + XH_BYTES);
    float*          accum = (float*)(ws + XH_BYTES + SIM_BYTES);

    k_convert<<<2048, 256, 0, stream>>>(x, Xh, accum);
    k_gemm<<<NUT, 256, 0, stream>>>(Xh, simh);
    k_stats<<<N_ROWS / 4, 256, 0, stream>>>(simh, targets, accum);
    k_final<<<1, 64, 0, stream>>>(accum, out);
}

// Round 9
// 147.811 us; speedup vs baseline: 1.0794x; 1.0682x over previous
//
#include <hip/hip_runtime.h>

// MarginDevianceLoss on MI355X.
// Pipeline: f32->f16 convert -> MFMA Gram (528 upper-triangle tiles, prefetch
// double-buffered LDS + XOR-swizzled staging/reads, mirror-write transpose)
//        -> per-row stats+loss (one wave/row) -> finalize.
// ws layout: [0,8MB) Xh fp16 [4096][1024]; [8MB,40MB) simh fp16 [4096][4096];
//            [40MB,+64B) float accumulators. Requires ws_size >= ~42MB.

#define N_ROWS 4096
#define DIM    1024
#define BM     128
#define BK     64
#define NTILE  32              // N_ROWS / BM
#define NUT    528             // NTILE*(NTILE+1)/2 upper-triangle tiles
#define NKT    (DIM / BK)      // 16 K-steps

typedef _Float16 half_t;
typedef __attribute__((ext_vector_type(8))) _Float16 half8;
typedef __attribute__((ext_vector_type(4))) float f32x4;
typedef __attribute__((ext_vector_type(4))) unsigned short ushort4v;

#define XH_BYTES  ((size_t)N_ROWS * DIM * 2)           // 8 MB
#define SIM_BYTES ((size_t)N_ROWS * N_ROWS * 2)        // 32 MB

__device__ __forceinline__ unsigned short f2h_bits(float f) {
    half_t h = (half_t)f;
    return __builtin_bit_cast(unsigned short, h);
}
__device__ __forceinline__ float h2f_bits(unsigned short u) {
    half_t h = __builtin_bit_cast(half_t, u);
    return (float)h;
}
// softplus via native v_exp/v_log (fast, ~1e-6 rel err; threshold is 1.5e-2)
__device__ __forceinline__ float sp_fast(float x) {
    return fmaxf(x, 0.f) + __logf(1.f + __expf(-fabsf(x)));
}
// full-wave (64-lane) butterfly sum; result in all lanes
__device__ __forceinline__ float wred(float v) {
#pragma unroll
    for (int m = 1; m < 64; m <<= 1) v += __shfl_xor(v, m, 64);
    return v;
}

// ---------------- convert: fp32 -> fp16, also zero the accumulators ----------
__global__ __launch_bounds__(256) void k_convert(const float* __restrict__ x,
                                                 unsigned short* __restrict__ xh,
                                                 float* __restrict__ accum) {
    if (blockIdx.x == 0 && threadIdx.x < 8) accum[threadIdx.x] = 0.f;
    int idx = blockIdx.x * 256 + threadIdx.x;          // 524288 threads, 8 elems each
    const float4* x4 = reinterpret_cast<const float4*>(x);
    float4 a = x4[2 * idx];
    float4 b = x4[2 * idx + 1];
    half8 h;
    h[0] = (half_t)a.x; h[1] = (half_t)a.y; h[2] = (half_t)a.z; h[3] = (half_t)a.w;
    h[4] = (half_t)b.x; h[5] = (half_t)b.y; h[6] = (half_t)b.z; h[7] = (half_t)b.w;
    *reinterpret_cast<half8*>(xh + 8 * idx) = h;
}

// ---------------- GEMM: sim = Xh * Xh^T (upper-triangle tiles + mirror) -------
// 1D grid of 528 tiles; triangular decode; 128x128 tile, BK=64, 4 waves (2x2).
// Prefetch 2-phase: STAGE(next) issued before COMPUTE(cur); one barrier/K-step
// (its implicit vmcnt(0) drains loads that had the whole compute to land).
// LDS XOR swizzle (slot ^= row&7): linear gload_lds dest + inverse-swizzled
// global SOURCE + swizzled ds_read addr (both-sides-or-neither rule).
__global__ __launch_bounds__(256) void k_gemm(const unsigned short* __restrict__ Xh,
                                              unsigned short* __restrict__ simh) {
    // XCD chunk swizzle (bijective: 528 % 8 == 0, 66 tiles per XCD)
    const int k0 = blockIdx.x;
    const int k  = (k0 & 7) * (NUT / 8) + (k0 >> 3);
    // triangular decode: row r with S(r)=r*(65-r)/2 tiles before it
    int r = (int)((65.0f - sqrtf(4225.0f - 8.0f * (float)k)) * 0.5f);
    while ((r + 1) * (65 - (r + 1)) / 2 <= k) ++r;
    while (r * (65 - r) / 2 > k) --r;
    const int by = r;
    const int bx = r + (k - r * (65 - r) / 2);

    __shared__ __align__(16) unsigned short As[2][BM * BK];
    __shared__ __align__(16) unsigned short Bs[2][BM * BK];
    const int t = threadIdx.x;
    const int lane = t & 63;
    const int wave = t >> 6;
    const int wr = wave >> 1, wc = wave & 1;
    const int brow = by * BM;
    const int bcol = bx * BM;

    f32x4 acc[4][4];
#pragma unroll
    for (int m = 0; m < 4; ++m)
#pragma unroll
        for (int n = 0; n < 4; ++n) acc[m][n] = (f32x4){0.f, 0.f, 0.f, 0.f};

    const char* xb = reinterpret_cast<const char*>(Xh);

    // stage one K-tile into buffer `buf`; source column pre-swizzled so that a
    // swizzled read (slot ^ row&7) returns linear data. LDS dest stays linear.
#define STAGE(buf, kt)                                                          \
    {                                                                           \
        _Pragma("unroll")                                                       \
        for (int i = 0; i < 4; ++i) {                                           \
            int off = i * 4096 + t * 16;                                        \
            int rr  = off >> 7;                                                 \
            int scb = ((((off >> 4) & 7) ^ (rr & 7)) << 4);                     \
            const char* gA = xb + (size_t)(brow + rr) * (DIM * 2) + (kt) * (BK * 2) + scb; \
            const char* gB = xb + (size_t)(bcol + rr) * (DIM * 2) + (kt) * (BK * 2) + scb; \
            __builtin_amdgcn_global_load_lds(                                   \
                (const __attribute__((address_space(1))) void*)gA,              \
                (__attribute__((address_space(3))) void*)((char*)As[buf] + off), 16, 0, 0); \
            __builtin_amdgcn_global_load_lds(                                   \
                (const __attribute__((address_space(1))) void*)gB,              \
                (__attribute__((address_space(3))) void*)((char*)Bs[buf] + off), 16, 0, 0); \
        }                                                                       \
    }

#define COMPUTE(buf)                                                            \
    {                                                                           \
        const char* Ab = (const char*)As[buf];                                  \
        const char* Bb = (const char*)Bs[buf];                                  \
        _Pragma("unroll")                                                       \
        for (int kk = 0; kk < 2; ++kk) {                                        \
            half8 a[4], b[4];                                                   \
            const int kb = kk * 64 + (lane >> 4) * 16;                          \
            _Pragma("unroll")                                                   \
            for (int m = 0; m < 4; ++m) {                                       \
                int ra = wr * 64 + m * 16 + (lane & 15);                        \
                a[m] = *reinterpret_cast<const half8*>(                         \
                    Ab + (((ra << 7) + kb) ^ ((ra & 7) << 4)));                 \
            }                                                                   \
            _Pragma("unroll")                                                   \
            for (int n = 0; n < 4; ++n) {                                       \
                int rb = wc * 64 + n * 16 + (lane & 15);                        \
                b[n] = *reinterpret_cast<const half8*>(                         \
                    Bb + (((rb << 7) + kb) ^ ((rb & 7) << 4)));                 \
            }                                                                   \
            _Pragma("unroll")                                                   \
            for (int m = 0; m < 4; ++m)                                         \
                _Pragma("unroll")                                               \
                for (int n = 0; n < 4; ++n)                                     \
                    acc[m][n] = __builtin_amdgcn_mfma_f32_16x16x32_f16(         \
                        a[m], b[n], acc[m][n], 0, 0, 0);                        \
        }                                                                       \
    }

    // prologue: stage tile 0, sync
    STAGE(0, 0);
    __syncthreads();
    int cur = 0;
    for (int kt = 0; kt < NKT - 1; ++kt) {
        STAGE(cur ^ 1, kt + 1);    // issue next-tile loads (latency hides under compute)
        COMPUTE(cur);
        __syncthreads();           // implicit vmcnt(0)+lgkmcnt(0): next tile ready
        cur ^= 1;
    }
    COMPUTE(cur);                  // last tile, no prefetch

#undef STAGE
#undef COMPUTE

    // epilogue: C/D layout col=lane&15, row=(lane>>4)*4+reg  [verified m89]
    const int fr = lane & 15, fq = lane >> 4;
#pragma unroll
    for (int m = 0; m < 4; ++m) {
#pragma unroll
        for (int n = 0; n < 4; ++n) {
            int col  = bcol + wc * 64 + n * 16 + fr;
            int row0 = brow + wr * 64 + m * 16 + fq * 4;
#pragma unroll
            for (int rr = 0; rr < 4; ++rr)
                simh[(size_t)(row0 + rr) * N_ROWS + col] = f2h_bits(acc[m][n][rr]);
            if (bx != by) {
                // mirror tile: sim[col][row0..row0+3] (exact transpose; identical
                // products, identical k-order). One packed 8B store per frag col.
                ushort4v p;
                p[0] = f2h_bits(acc[m][n][0]);
                p[1] = f2h_bits(acc[m][n][1]);
                p[2] = f2h_bits(acc[m][n][2]);
                p[3] = f2h_bits(acc[m][n][3]);
                *reinterpret_cast<ushort4v*>(simh + (size_t)col * N_ROWS + row0) = p;
            }
        }
    }
}

// ---------------- per-row stats + loss: one wave per row ----------------------
__global__ __launch_bounds__(256) void k_stats(const unsigned short* __restrict__ simh,
                                               const int* __restrict__ targets,
                                               float* __restrict__ accum) {
    __shared__ float part[4][8];
    const int t = threadIdx.x;
    const int lane = t & 63;
    const int w = t >> 6;
    const int i = blockIdx.x * 4 + w;                  // this wave's row
    const int ti = targets[i];

    const uint4* r4  = reinterpret_cast<const uint4*>(simh + (size_t)i * N_ROWS);
    const int4*  tg4 = reinterpret_cast<const int4*>(targets);

    float s[8][8];
    unsigned int mpos[8];
    float ps = 0.f, ps2 = 0.f, ns = 0.f, ns2 = 0.f, pc = 0.f, nc = 0.f;

#pragma unroll
    for (int j = 0; j < 8; ++j) {
        const int ci = j * 64 + lane;                  // uint4 index; cols 8*ci..+7
        uint4 v  = r4[ci];
        int4 ta = tg4[2 * ci];
        int4 tb = tg4[2 * ci + 1];
        unsigned m = 0;
        m |= (ta.x == ti) ? 1u   : 0u;
        m |= (ta.y == ti) ? 2u   : 0u;
        m |= (ta.z == ti) ? 4u   : 0u;
        m |= (ta.w == ti) ? 8u   : 0u;
        m |= (tb.x == ti) ? 16u  : 0u;
        m |= (tb.y == ti) ? 32u  : 0u;
        m |= (tb.z == ti) ? 64u  : 0u;
        m |= (tb.w == ti) ? 128u : 0u;
        mpos[j] = m;
        unsigned int uw0 = v.x, uw1 = v.y, uw2 = v.z, uw3 = v.w;
        s[j][0] = h2f_bits((unsigned short)(uw0 & 0xffff));
        s[j][1] = h2f_bits((unsigned short)(uw0 >> 16));
        s[j][2] = h2f_bits((unsigned short)(uw1 & 0xffff));
        s[j][3] = h2f_bits((unsigned short)(uw1 >> 16));
        s[j][4] = h2f_bits((unsigned short)(uw2 & 0xffff));
        s[j][5] = h2f_bits((unsigned short)(uw2 >> 16));
        s[j][6] = h2f_bits((unsigned short)(uw3 & 0xffff));
        s[j][7] = h2f_bits((unsigned short)(uw3 >> 16));
        const int c0 = ci * 8;
#pragma unroll
        for (int e = 0; e < 8; ++e) {
            float sv = s[j][e];
            bool pos  = (m >> e) & 1;
            bool diag = (c0 + e) == i;
            if (pos) {
                if (!diag) { ps += sv; ps2 = fmaf(sv, sv, ps2); pc += 1.f; }
            } else {
                ns += sv; ns2 = fmaf(sv, sv, ns2); nc += 1.f;
            }
        }
    }
    ps = wred(ps); ps2 = wred(ps2); pc = wred(pc);
    ns = wred(ns); ns2 = wred(ns2); nc = wred(nc);

    float pmean = ps / pc;
    float pstd  = sqrtf(fmaxf(ps2 / pc - pmean * pmean, 0.f));
    float nmean = ns / nc;
    float nstd  = sqrtf(fmaxf(ns2 / nc - nmean * nmean, 0.f));
    float inter = (pstd * pmean + nstd * nmean) / (pstd + nstd);
    float thr   = pmean - 1.5f * pstd;

    float pl = 0.f, nl = 0.f, kc = 0.f;
#pragma unroll
    for (int j = 0; j < 8; ++j) {
        const int c0 = (j * 64 + lane) * 8;
        unsigned m = mpos[j];
#pragma unroll
        for (int e = 0; e < 8; ++e) {
            float sv = s[j][e];
            float d  = sv - inter;
            bool pos  = (m >> e) & 1;
            bool diag = (c0 + e) == i;
            if (pos) {
                if (!diag) pl += sp_fast(-2.f * d);
            } else if (sv > thr) {
                kc += 1.f;
                nl += sp_fast(50.f * d);
            }
        }
    }
    pl = wred(pl); nl = wred(nl); kc = wred(kc);

    if (lane == 0) {
        bool valid = kc >= 1.f;
        part[w][0] = valid ? (pl / pc + 0.04f * nl / fmaxf(kc, 1.f)) : 0.f;
        part[w][1] = valid ? 0.f : 1.f;
        part[w][2] = ps;
        part[w][3] = pc;
        part[w][4] = ns;
        part[w][5] = nc;
    }
    __syncthreads();
    if (t < 6) {
        float v = part[0][t] + part[1][t] + part[2][t] + part[3][t];
        atomicAdd(&accum[t], v);
    }
}

// ---------------- finalize ----------------------------------------------------
__global__ void k_final(const float* __restrict__ acc, float* __restrict__ out) {
    if (threadIdx.x == 0) {
        out[0] = acc[0] / (float)N_ROWS;   // loss
        out[1] = acc[1] / (float)N_ROWS;   // prec
        out[2] = acc[2] / acc[3];          // pos_d
        out[3] = acc[4] / acc[5];          // neg_d
    }
}

extern "C" void kernel_launch(void* const* d_in, const int* in_sizes, int n_in,
                              void* d_out, int out_size, void* d_ws, size_t ws_size,
                              hipStream_t stream) {
    const float* x       = (const float*)d_in[0];
    const int*   targets = (const int*)d_in[1];
    float*       out     = (float*)d_out;
    char*        ws      = (char*)d_ws;

    unsigned short* Xh    = (unsigned short*)ws;
    unsigned short* simh  = (unsigned short*)(ws + XH_BYTES);
    float*          accum = (float*)(ws + XH_BYTES + SIM_BYTES);

    k_convert<<<2048, 256, 0, stream>>>(x, Xh, accum);
    k_gemm<<<NUT, 256, 0, stream>>>(Xh, simh);
    k_stats<<<N_ROWS / 4, 256, 0, stream>>>(simh, targets, accum);
    k_final<<<1, 64, 0, stream>>>(accum, out);
}